// Round 3
// baseline (20057.802 us; speedup 1.0000x reference)
//
#include <hip/hip_runtime.h>
#include <math.h>

// ---------------- problem constants ----------------
#define TDIM 1024          // T
#define DDIM 1024          // D (= H*HD)
#define NH   16
#define HDIM 64
#define BB   4
#define NLAYER 6
#define NTOK (BB*TDIM)     // 4096 rows
#define NELEM (NTOK*DDIM)  // 4,194,304

// ---------------- embedding: x = tok[idx] + pos ----------------
__global__ __launch_bounds__(256)
void k_embed(const int* __restrict__ idx, const float* __restrict__ tok,
             const float* __restrict__ pos, float* __restrict__ x) {
  int e4 = blockIdx.x * 256 + threadIdx.x;   // 1M threads, 4 elems each
  int e  = e4 * 4;
  int r  = e >> 10;            // token row 0..4095
  int d  = e & 1023;
  int tp = r & (TDIM - 1);     // position within sequence
  int id = idx[r];
  float4 a = *reinterpret_cast<const float4*>(&tok[(size_t)id * DDIM + d]);
  float4 p = *reinterpret_cast<const float4*>(&pos[(size_t)tp * DDIM + d]);
  float4 o = make_float4(a.x + p.x, a.y + p.y, a.z + p.z, a.w + p.w);
  reinterpret_cast<float4*>(x)[e4] = o;
}

// ---------------- full-tensor layernorm: 2-stage fp64 reduction ----------------
__global__ __launch_bounds__(256)
void k_reduce1(const float* __restrict__ x, double* __restrict__ part) {
  int t = threadIdx.x;
  size_t base = (size_t)blockIdx.x * 1024;
  double s = 0.0, ss = 0.0;
  #pragma unroll
  for (int it = 0; it < 4; ++it) {
    double v = (double)x[base + it * 256 + t];
    s += v; ss += v * v;
  }
  __shared__ double rs[256], rq[256];
  rs[t] = s; rq[t] = ss; __syncthreads();
  for (int w = 128; w > 0; w >>= 1) {
    if (t < w) { rs[t] += rs[t + w]; rq[t] += rq[t + w]; }
    __syncthreads();
  }
  if (t == 0) { part[blockIdx.x * 2] = rs[0]; part[blockIdx.x * 2 + 1] = rq[0]; }
}

__global__ __launch_bounds__(1024)
void k_reduce2(const double* __restrict__ part, double* __restrict__ stats) {
  int t = threadIdx.x;
  double s = 0.0, ss = 0.0;
  #pragma unroll
  for (int it = 0; it < 4; ++it) {
    int p = it * 1024 + t;
    s  += part[p * 2];
    ss += part[p * 2 + 1];
  }
  __shared__ double rs[1024], rq[1024];
  rs[t] = s; rq[t] = ss; __syncthreads();
  for (int w = 512; w > 0; w >>= 1) {
    if (t < w) { rs[t] += rs[t + w]; rq[t] += rq[t + w]; }
    __syncthreads();
  }
  if (t == 0) {
    double mu  = rs[0] / (double)NELEM;
    double var = rq[0] / (double)NELEM - mu * mu;
    stats[0] = mu;
    stats[1] = 1.0 / sqrt(var + 1e-5);
  }
}

__global__ __launch_bounds__(256)
void k_norm4(const float* __restrict__ x, const double* __restrict__ stats,
             float* __restrict__ y) {
  int e4 = blockIdx.x * 256 + threadIdx.x;
  double mu = stats[0], rs = stats[1];
  float4 v = reinterpret_cast<const float4*>(x)[e4];
  float4 o = make_float4((float)(((double)v.x - mu) * rs),
                         (float)(((double)v.y - mu) * rs),
                         (float)(((double)v.z - mu) * rs),
                         (float)(((double)v.w - mu) * rs));
  reinterpret_cast<float4*>(y)[e4] = o;
}

// t1 += proj (in place)
__global__ __launch_bounds__(256)
void k_add4(float* __restrict__ t1, const float* __restrict__ proj) {
  int e4 = blockIdx.x * 256 + threadIdx.x;
  float4 a = reinterpret_cast<const float4*>(t1)[e4];
  float4 b = reinterpret_cast<const float4*>(proj)[e4];
  float4 o = make_float4(a.x + b.x, a.y + b.y, a.z + b.z, a.w + b.w);
  reinterpret_cast<float4*>(t1)[e4] = o;
}

// x = 2*((t1 - mu)*rstd + proj)
__global__ __launch_bounds__(256)
void k_combine4(const float* __restrict__ t1, const float* __restrict__ proj,
                const double* __restrict__ stats, float* __restrict__ x) {
  int e4 = blockIdx.x * 256 + threadIdx.x;
  double mu = stats[0], rs = stats[1];
  float4 a = reinterpret_cast<const float4*>(t1)[e4];
  float4 b = reinterpret_cast<const float4*>(proj)[e4];
  float4 o = make_float4((float)(2.0 * (((double)a.x - mu) * rs + (double)b.x)),
                         (float)(2.0 * (((double)a.y - mu) * rs + (double)b.y)),
                         (float)(2.0 * (((double)a.z - mu) * rs + (double)b.z)),
                         (float)(2.0 * (((double)a.w - mu) * rs + (double)b.w)));
  reinterpret_cast<float4*>(x)[e4] = o;
}

// out_fp32 = (x - mu)*rstd
__global__ __launch_bounds__(256)
void k_norm_out(const float* __restrict__ x, const double* __restrict__ stats,
                float* __restrict__ out) {
  int e4 = blockIdx.x * 256 + threadIdx.x;
  double mu = stats[0], rs = stats[1];
  float4 v = reinterpret_cast<const float4*>(x)[e4];
  float4 o = make_float4((float)(((double)v.x - mu) * rs),
                         (float)(((double)v.y - mu) * rs),
                         (float)(((double)v.z - mu) * rs),
                         (float)(((double)v.w - mu) * rs));
  reinterpret_cast<float4*>(out)[e4] = o;
}

// ---------------- GEMM (fp32 in, fp64 accumulate): C = A[4096x1024] * B[1024x1024] ----
// 64x64 tile, BK=16, 256 threads, 4x4/thread.
// scatter=1: write C to [B,H,T,HD] layout (for q/k/v); scatter=0: plain row-major.
__global__ __launch_bounds__(256)
void k_gemm(const float* __restrict__ A, const float* __restrict__ Bm,
            float* __restrict__ C, int scatter) {
  __shared__ float As[16][64];
  __shared__ float Bs[16][64];
  int t  = threadIdx.x;
  int m0 = blockIdx.y * 64;
  int n0 = blockIdx.x * 64;
  int tx = t & 15, ty = t >> 4;
  int ar = t >> 2;            // A tile row 0..63
  int ak = (t & 3) * 4;       // A tile k-chunk
  int br = t >> 4;            // B tile k-row 0..15
  int bc = (t & 15) * 4;      // B tile col-chunk
  double acc[4][4] = {};

  for (int kk = 0; kk < DDIM; kk += 16) {
    float4 av = *reinterpret_cast<const float4*>(&A[(size_t)(m0 + ar) * DDIM + kk + ak]);
    float4 bv = *reinterpret_cast<const float4*>(&Bm[(size_t)(kk + br) * DDIM + n0 + bc]);
    __syncthreads();
    As[ak + 0][ar] = av.x; As[ak + 1][ar] = av.y;
    As[ak + 2][ar] = av.z; As[ak + 3][ar] = av.w;
    Bs[br][bc + 0] = bv.x; Bs[br][bc + 1] = bv.y;
    Bs[br][bc + 2] = bv.z; Bs[br][bc + 3] = bv.w;
    __syncthreads();
    #pragma unroll
    for (int k = 0; k < 16; ++k) {
      float4 a4 = *reinterpret_cast<const float4*>(&As[k][ty * 4]);
      float4 b4 = *reinterpret_cast<const float4*>(&Bs[k][tx * 4]);
      double ad[4] = {(double)a4.x, (double)a4.y, (double)a4.z, (double)a4.w};
      double bd[4] = {(double)b4.x, (double)b4.y, (double)b4.z, (double)b4.w};
      #pragma unroll
      for (int i = 0; i < 4; ++i)
        #pragma unroll
        for (int j = 0; j < 4; ++j)
          acc[i][j] += ad[i] * bd[j];
    }
  }

  #pragma unroll
  for (int i = 0; i < 4; ++i) {
    int r  = m0 + ty * 4 + i;
    int b  = r >> 10;           // batch
    int tp = r & 1023;          // seq pos
    #pragma unroll
    for (int j = 0; j < 4; ++j) {
      int c = n0 + tx * 4 + j;
      float val = (float)acc[i][j];
      if (scatter) {
        int h = c >> 6, d = c & 63;
        C[((size_t)((b * NH + h) * TDIM + tp)) * HDIM + d] = val;
      } else {
        C[(size_t)r * DDIM + c] = val;
      }
    }
  }
}

// ---------------- attention (transposed-score variant), fp64 internal ----------------
// scores s[j] = k[i] . q[j] * 0.125 for j<=i; softmax over j; out = sum p_j v[j]
// one block per (b,h,i); q,k,v in [B,H,T,HD] fp32; out -> [B,T, h*64+d] fp32
__global__ __launch_bounds__(256)
void k_attn(const float* __restrict__ q, const float* __restrict__ k,
            const float* __restrict__ v, float* __restrict__ attout) {
  int i  = blockIdx.x;
  int bh = blockIdx.y;           // b*16 + h
  int b  = bh >> 4, h = bh & 15;
  const float* qh = q + (size_t)bh * TDIM * HDIM;
  const float* kh = k + (size_t)bh * TDIM * HDIM;
  const float* vh = v + (size_t)bh * TDIM * HDIM;

  __shared__ double kv[HDIM];
  __shared__ double s[TDIM];
  __shared__ double red[256];
  int t = threadIdx.x;
  if (t < HDIM) kv[t] = (double)kh[(size_t)i * HDIM + t];
  __syncthreads();

  int n = i + 1;
  // pass A: scores + local max (fp64)
  double mloc = -1e300;
  for (int j = t; j < n; j += 256) {
    const float* qr = qh + (size_t)j * HDIM;
    double acc = 0.0;
    #pragma unroll
    for (int d = 0; d < HDIM; d += 4) {
      float4 qv = *reinterpret_cast<const float4*>(qr + d);
      acc += (double)qv.x * kv[d]     + (double)qv.y * kv[d + 1]
           + (double)qv.z * kv[d + 2] + (double)qv.w * kv[d + 3];
    }
    acc *= 0.125;
    s[j] = acc;
    mloc = fmax(mloc, acc);
  }
  red[t] = mloc; __syncthreads();
  for (int w = 128; w > 0; w >>= 1) {
    if (t < w) red[t] = fmax(red[t], red[t + w]);
    __syncthreads();
  }
  double m = red[0];
  __syncthreads();

  // exp + sum (fp64)
  double lloc = 0.0;
  for (int j = t; j < n; j += 256) {
    double e = exp(s[j] - m);
    s[j] = e;
    lloc += e;
  }
  red[t] = lloc; __syncthreads();
  for (int w = 128; w > 0; w >>= 1) {
    if (t < w) red[t] += red[t + w];
    __syncthreads();
  }
  double inv_l = 1.0 / red[0];
  __syncthreads();

  // pass B: PV (fp64). lane d = t&63, j-chunk = t>>6 (4 chunks)
  int d = t & 63, ch = t >> 6;
  double acc = 0.0;
  for (int j = ch; j < n; j += 4)
    acc += s[j] * (double)vh[(size_t)j * HDIM + d];
  red[t] = acc; __syncthreads();
  if (t < 64) {
    double tot = red[t] + red[t + 64] + red[t + 128] + red[t + 192];
    attout[((size_t)(b * TDIM + i)) * DDIM + h * HDIM + d] = (float)(tot * inv_l);
  }
}

// ---------------- launcher ----------------
extern "C" void kernel_launch(void* const* d_in, const int* in_sizes, int n_in,
                              void* d_out, int out_size, void* d_ws, size_t ws_size,
                              hipStream_t stream) {
  (void)in_sizes; (void)n_in; (void)out_size; (void)ws_size;
  const int*   idx = (const int*)d_in[0];
  const float* tok = (const float*)d_in[1];
  const float* pos = (const float*)d_in[2];
  const float* wq  = (const float*)d_in[3];
  const float* wk  = (const float*)d_in[4];
  const float* wv  = (const float*)d_in[5];
  const float* wo  = (const float*)d_in[6];
  // d_in[7..9] (w_in, w_out, lm_head) are dead code in the reference
  float* out = (float*)d_out;

  float* ws   = (float*)d_ws;
  float* x    = ws;                 // [4096,1024]; also reused for att
  float* xn   = x   + NELEM;        // [4096,1024]  (also t1 = xn+proj)
  float* q    = xn  + NELEM;        // [B,H,T,HD]   (also reused for proj)
  float* k    = q   + NELEM;        // [B,H,T,HD]
  float* v    = k   + NELEM;        // [B,H,T,HD]
  float* att  = x;                  // alias: x dead between norm(x) and combine
  float* proj = q;                  // alias: q dead once att computed
  double* part  = (double*)(v + NELEM);   // [4096*2] fp64 partials (64 KB)
  double* stats = part + 8192;            // [2] fp64 (mu, rstd)

  dim3 ggemm(DDIM / 64, NTOK / 64); // (16, 64)
  dim3 gattn(TDIM, BB * NH);        // (1024, 64)

  k_embed<<<4096, 256, 0, stream>>>(idx, tok, pos, x);

  for (int l = 0; l < NLAYER; ++l) {
    // xn = ln_all(x)
    k_reduce1<<<4096, 256, 0, stream>>>(x, part);
    k_reduce2<<<1, 1024, 0, stream>>>(part, stats);
    k_norm4<<<4096, 256, 0, stream>>>(x, stats, xn);
    // q,k,v (scattered to [B,H,T,HD])
    k_gemm<<<ggemm, 256, 0, stream>>>(xn, wq, q, 1);
    k_gemm<<<ggemm, 256, 0, stream>>>(xn, wk, k, 1);
    k_gemm<<<ggemm, 256, 0, stream>>>(xn, wv, v, 1);
    // attention -> att [4096,1024] (x-alias; x is dead here)
    k_attn<<<gattn, 256, 0, stream>>>(q, k, v, att);
    // proj = att @ Wo   (plain layout; writes into q-alias)
    k_gemm<<<ggemm, 256, 0, stream>>>(att, wo, proj, 0);
    // t1 = xn + proj (in place in xn)
    k_add4<<<4096, 256, 0, stream>>>(xn, proj);
    // x = 2*(ln_all(t1) + proj)
    k_reduce1<<<4096, 256, 0, stream>>>(xn, part);
    k_reduce2<<<1, 1024, 0, stream>>>(part, stats);
    k_combine4<<<4096, 256, 0, stream>>>(xn, proj, stats, x);
  }

  // out = fp32(ln_all(x))
  k_reduce1<<<4096, 256, 0, stream>>>(x, part);
  k_reduce2<<<1, 1024, 0, stream>>>(part, stats);
  k_norm_out<<<4096, 256, 0, stream>>>(x, stats, out);
}